// Round 3
// baseline (452.777 us; speedup 1.0000x reference)
//
#include <hip/hip_runtime.h>

#define S_TOK 3072   // 64*48
#define NHEADS 8

typedef __attribute__((ext_vector_type(8))) short short8;
typedef __attribute__((ext_vector_type(4))) float floatx4;
typedef __attribute__((ext_vector_type(4))) unsigned short ushortx4;

__device__ __forceinline__ unsigned short f2bf(float f) {
  union { float f; unsigned u; } v; v.f = f;
  unsigned r = v.u + 0x7fffu + ((v.u >> 16) & 1u);   // RTN-even
  return (unsigned short)(r >> 16);
}

// ---------------- Pass A: QKV projection (f32 math, bf16 out) ----------------
// X [6144][512] @ W [512][1536] -> Q (pre-scaled), K, V row-major [bh][s][64]
__global__ __launch_bounds__(256) void ga_qkv_gemm(
    const float* __restrict__ X, const float* __restrict__ W,
    unsigned short* __restrict__ Q, unsigned short* __restrict__ K,
    unsigned short* __restrict__ V) {
  const int tid = threadIdx.x;
  const int ty = tid >> 4, tx = tid & 15;
  const int m0 = blockIdx.x * 64;
  const int n0 = blockIdx.y * 64;
  __shared__ float As[16][68];   // [k][m]
  __shared__ float Bs[16][68];   // [k][n]
  float acc[4][4] = {};
  const int lm = tid >> 2;   // 0..63
  const int lk4 = tid & 3;   // 0..3
  const int bk = tid >> 4;   // 0..15
  const int bn4 = tid & 15;  // 0..15
  for (int k0 = 0; k0 < 512; k0 += 16) {
    float4 a = *(const float4*)&X[(size_t)(m0 + lm) * 512 + k0 + lk4 * 4];
    As[lk4 * 4 + 0][lm] = a.x;
    As[lk4 * 4 + 1][lm] = a.y;
    As[lk4 * 4 + 2][lm] = a.z;
    As[lk4 * 4 + 3][lm] = a.w;
    *(float4*)&Bs[bk][bn4 * 4] =
        *(const float4*)&W[(size_t)(k0 + bk) * 1536 + n0 + bn4 * 4];
    __syncthreads();
#pragma unroll
    for (int kk = 0; kk < 16; ++kk) {
      float4 av = *(const float4*)&As[kk][ty * 4];
      float4 bv = *(const float4*)&Bs[kk][tx * 4];
      float aa[4] = {av.x, av.y, av.z, av.w};
      float bb[4] = {bv.x, bv.y, bv.z, bv.w};
#pragma unroll
      for (int i = 0; i < 4; ++i)
#pragma unroll
        for (int j = 0; j < 4; ++j)
          acc[i][j] = fmaf(aa[i], bb[j], acc[i][j]);
    }
    __syncthreads();
  }
  const int which = n0 >> 9;        // 0=Q 1=K 2=V
  const int h = (n0 >> 6) & 7;
  const int b = m0 / S_TOK;
  const int s0 = m0 % S_TOK;
  const int bh = b * NHEADS + h;
  unsigned short* dst =
      ((which == 0) ? Q : (which == 1) ? K : V) + (size_t)bh * S_TOK * 64;
  const float qscale = (which == 0) ? 0.18033688f : 1.0f;  // 1/8 * log2(e)
#pragma unroll
  for (int i = 0; i < 4; ++i) {
    ushortx4 o = {f2bf(acc[i][0] * qscale), f2bf(acc[i][1] * qscale),
                  f2bf(acc[i][2] * qscale), f2bf(acc[i][3] * qscale)};
    *(ushortx4*)&dst[(size_t)(s0 + ty * 4 + i) * 64 + tx * 4] = o;
  }
}

// ---------------- Pass A2: V transpose -> Vt [bh][d][s] ----------------
__global__ __launch_bounds__(256) void ga_vtrans(
    const unsigned short* __restrict__ V, unsigned short* __restrict__ Vt) {
  const int t = threadIdx.x;
  const int s0 = blockIdx.x * 64;
  const int bh = blockIdx.y;
  __shared__ unsigned short Ts[64][68];
  const unsigned short* vp = V + ((size_t)bh * S_TOK + s0) * 64;
#pragma unroll
  for (int it = 0; it < 2; ++it) {
    int s = it * 32 + (t >> 3);
    int d8 = t & 7;
    short8 v = *(const short8*)&vp[(size_t)s * 64 + d8 * 8];
    ushortx4 lo = {(unsigned short)v[0], (unsigned short)v[1],
                   (unsigned short)v[2], (unsigned short)v[3]};
    ushortx4 hi = {(unsigned short)v[4], (unsigned short)v[5],
                   (unsigned short)v[6], (unsigned short)v[7]};
    *(ushortx4*)&Ts[s][d8 * 8] = lo;
    *(ushortx4*)&Ts[s][d8 * 8 + 4] = hi;
  }
  __syncthreads();
  const int w = t >> 6, l = t & 63;
  unsigned short* dst = Vt + (size_t)bh * 64 * S_TOK + s0;
#pragma unroll
  for (int dd = 0; dd < 16; ++dd) {
    int d = w * 16 + dd;
    dst[(size_t)d * S_TOK + l] = Ts[l][d];
  }
}

// ---------------- Pass B: split-K MFMA flash attention ----------------
// grid (48 qtiles, 16 bh, nsplit), block 256 = 4 waves; wave owns 16 q-rows.
// Q pre-scaled by (1/8)*log2e; tables pre-scaled by log2e; exp2-space softmax.
// Writes unnormalized O partials + (m,l) per row.
__global__ __launch_bounds__(256) void ga_attn_mfma(
    const unsigned short* __restrict__ Q, const unsigned short* __restrict__ K,
    const unsigned short* __restrict__ Vt, const float* __restrict__ rowtab,
    const float* __restrict__ coltab, float* __restrict__ Opart,
    float2* __restrict__ Ml, int ktiles) {
  const int tid = threadIdx.x;
  const int w = tid >> 6;        // wave 0..3
  const int l = tid & 63;        // lane
  const int g = l >> 4;          // lane group 0..3
  const int ln = l & 15;         // lane 0..15
  const int q0 = blockIdx.x * 64;
  const int bh = blockIdx.y;
  const int sp = blockIdx.z;
  const int h = bh & 7;
  const int b = bh >> 3;
  const int k_begin = sp * ktiles * 64;

  __shared__ float rtab[127];
  __shared__ float ctab[95];
  __shared__ unsigned short Plds[4][1024];  // per-wave 16x64 bf16, swizzled
  for (int i = tid; i < 127; i += 256) rtab[i] = rowtab[i * 8 + h] * 1.44269504f;
  for (int i = tid; i < 95; i += 256) ctab[i] = coltab[i * 8 + h] * 1.44269504f;
  __syncthreads();

  const unsigned short* Qp = Q + (size_t)bh * S_TOK * 64;
  const unsigned short* Kp = K + (size_t)bh * S_TOK * 64;
  const unsigned short* Vp = Vt + (size_t)bh * 64 * S_TOK;

  const int qrow = q0 + w * 16 + ln;
  short8 qf0 = *(const short8*)&Qp[(size_t)qrow * 64 + g * 8];
  short8 qf1 = *(const short8*)&Qp[(size_t)qrow * 64 + 32 + g * 8];

  int qr[4], qc[4];
#pragma unroll
  for (int r = 0; r < 4; ++r) {
    int q = q0 + w * 16 + g * 4 + r;
    qr[r] = q / 48;
    qc[r] = q - qr[r] * 48;
  }

  floatx4 o_acc[4] = {floatx4{0.f, 0.f, 0.f, 0.f}, floatx4{0.f, 0.f, 0.f, 0.f},
                      floatx4{0.f, 0.f, 0.f, 0.f}, floatx4{0.f, 0.f, 0.f, 0.f}};
  float m_i[4] = {-1e30f, -1e30f, -1e30f, -1e30f};
  float l_i[4] = {0.f, 0.f, 0.f, 0.f};

  for (int kt = 0; kt < ktiles; ++kt) {
    const int k0 = k_begin + kt * 64;
    // ---- S = Q K^T (already in log2-units thanks to pre-scaled Q)
    floatx4 s_acc[4] = {floatx4{0.f, 0.f, 0.f, 0.f}, floatx4{0.f, 0.f, 0.f, 0.f},
                        floatx4{0.f, 0.f, 0.f, 0.f}, floatx4{0.f, 0.f, 0.f, 0.f}};
#pragma unroll
    for (int t = 0; t < 4; ++t) {
      const unsigned short* kp = &Kp[(size_t)(k0 + t * 16 + ln) * 64 + g * 8];
      short8 kf0 = *(const short8*)kp;
      short8 kf1 = *(const short8*)(kp + 32);
      s_acc[t] = __builtin_amdgcn_mfma_f32_16x16x32_bf16(qf0, kf0, s_acc[t], 0, 0, 0);
      s_acc[t] = __builtin_amdgcn_mfma_f32_16x16x32_bf16(qf1, kf1, s_acc[t], 0, 0, 0);
    }
    // ---- rel-pos bias; C layout: row=g*4+r, col=t*16+ln
    float p[4][4];
#pragma unroll
    for (int t = 0; t < 4; ++t) {
      int k = k0 + t * 16 + ln;
      int kr = k / 48;
      int kc = k - kr * 48;
#pragma unroll
      for (int r = 0; r < 4; ++r)
        p[t][r] = s_acc[t][r] + rtab[qr[r] - kr + 63] + ctab[qc[r] - kc + 47];
    }
    // ---- online softmax per row
#pragma unroll
    for (int r = 0; r < 4; ++r) {
      float mx = fmaxf(fmaxf(p[0][r], p[1][r]), fmaxf(p[2][r], p[3][r]));
      mx = fmaxf(mx, __shfl_xor(mx, 1));
      mx = fmaxf(mx, __shfl_xor(mx, 2));
      mx = fmaxf(mx, __shfl_xor(mx, 4));
      mx = fmaxf(mx, __shfl_xor(mx, 8));
      float mnew = fmaxf(m_i[r], mx);
      float alpha = __builtin_amdgcn_exp2f(m_i[r] - mnew);
      m_i[r] = mnew;
      float s = 0.f;
#pragma unroll
      for (int t = 0; t < 4; ++t) {
        float e = __builtin_amdgcn_exp2f(p[t][r] - mnew);
        p[t][r] = e;
        s += e;
      }
      s += __shfl_xor(s, 1);
      s += __shfl_xor(s, 2);
      s += __shfl_xor(s, 4);
      s += __shfl_xor(s, 8);
      l_i[r] = l_i[r] * alpha + s;
      o_acc[0][r] *= alpha;
      o_acc[1][r] *= alpha;
      o_acc[2][r] *= alpha;
      o_acc[3][r] *= alpha;
    }
    // ---- P (bf16) -> per-wave LDS, XOR-swizzled; read back as A-frags
#pragma unroll
    for (int t = 0; t < 4; ++t)
#pragma unroll
      for (int r = 0; r < 4; ++r) {
        int row = g * 4 + r;
        int col = t * 16 + ln;
        Plds[w][(row * 64 + col) ^ ((row & 7) << 3)] = f2bf(p[t][r]);
      }
    short8 pf0 = *(const short8*)&Plds[w][(ln * 64 + g * 8) ^ ((ln & 7) << 3)];
    short8 pf1 = *(const short8*)&Plds[w][(ln * 64 + 32 + g * 8) ^ ((ln & 7) << 3)];
    // ---- O += P V
#pragma unroll
    for (int t = 0; t < 4; ++t) {
      const unsigned short* vp = &Vp[(size_t)(t * 16 + ln) * S_TOK + k0 + g * 8];
      short8 vf0 = *(const short8*)vp;
      short8 vf1 = *(const short8*)(vp + 32);
      o_acc[t] = __builtin_amdgcn_mfma_f32_16x16x32_bf16(pf0, vf0, o_acc[t], 0, 0, 0);
      o_acc[t] = __builtin_amdgcn_mfma_f32_16x16x32_bf16(pf1, vf1, o_acc[t], 0, 0, 0);
    }
  }
  // ---- epilogue: store unnormalized partials + (m, l)
#pragma unroll
  for (int r = 0; r < 4; ++r) {
    int q = q0 + w * 16 + g * 4 + r;
    size_t row = (size_t)(sp * 16 + bh) * S_TOK + q;
    float* dst = &Opart[row * 64 + ln];
    dst[0] = o_acc[0][r];
    dst[16] = o_acc[1][r];
    dst[32] = o_acc[2][r];
    dst[48] = o_acc[3][r];
    if (ln == 0) Ml[row] = make_float2(m_i[r], l_i[r]);
  }
}

// ------- Pass C: combine split-K partials fused into output projection -------
// A[m][k] = combined CTX; Out = A @ W  (f32)
template <int NS>
__global__ __launch_bounds__(256) void ga_out_gemm_combine(
    const float* __restrict__ Opart, const float2* __restrict__ Ml,
    const float* __restrict__ W, float* __restrict__ Out) {
  const int tid = threadIdx.x;
  const int ty = tid >> 4, tx = tid & 15;
  const int m0 = blockIdx.x * 64;
  const int n0 = blockIdx.y * 64;
  __shared__ float As[16][68];
  __shared__ float Bs[16][68];
  float acc[4][4] = {};
  const int lm = tid >> 2, lk4 = tid & 3;
  const int bk = tid >> 4, bn4 = tid & 15;
  const int m = m0 + lm;
  const int b = m / S_TOK;
  const int q = m - b * S_TOK;
  for (int k0 = 0; k0 < 512; k0 += 16) {
    // --- A stage with on-the-fly split-K combine
    {
      const int kk = k0 + lk4 * 4;
      const int h = kk >> 6;
      const int d = kk & 63;
      const int bh = b * 8 + h;
      float2 mls[NS];
      float mstar = -1e30f;
#pragma unroll
      for (int s = 0; s < NS; ++s) {
        mls[s] = Ml[(size_t)(s * 16 + bh) * S_TOK + q];
        mstar = fmaxf(mstar, mls[s].x);
      }
      float ax = 0.f, ay = 0.f, az = 0.f, aw = 0.f, wsum = 0.f;
#pragma unroll
      for (int s = 0; s < NS; ++s) {
        float wgt = exp2f(mls[s].x - mstar);
        const float4 o = *(const float4*)&Opart[((size_t)(s * 16 + bh) * S_TOK + q) * 64 + d];
        ax = fmaf(wgt, o.x, ax);
        ay = fmaf(wgt, o.y, ay);
        az = fmaf(wgt, o.z, az);
        aw = fmaf(wgt, o.w, aw);
        wsum = fmaf(wgt, mls[s].y, wsum);
      }
      float inv = 1.0f / wsum;
      As[lk4 * 4 + 0][lm] = ax * inv;
      As[lk4 * 4 + 1][lm] = ay * inv;
      As[lk4 * 4 + 2][lm] = az * inv;
      As[lk4 * 4 + 3][lm] = aw * inv;
    }
    *(float4*)&Bs[bk][bn4 * 4] =
        *(const float4*)&W[(size_t)(k0 + bk) * 512 + n0 + bn4 * 4];
    __syncthreads();
#pragma unroll
    for (int kk = 0; kk < 16; ++kk) {
      float4 av = *(const float4*)&As[kk][ty * 4];
      float4 bv = *(const float4*)&Bs[kk][tx * 4];
      float aa[4] = {av.x, av.y, av.z, av.w};
      float bb[4] = {bv.x, bv.y, bv.z, bv.w};
#pragma unroll
      for (int i = 0; i < 4; ++i)
#pragma unroll
        for (int j = 0; j < 4; ++j)
          acc[i][j] = fmaf(aa[i], bb[j], acc[i][j]);
    }
    __syncthreads();
  }
#pragma unroll
  for (int i = 0; i < 4; ++i) {
    float4 o = make_float4(acc[i][0], acc[i][1], acc[i][2], acc[i][3]);
    *(float4*)&Out[(size_t)(m0 + ty * 4 + i) * 512 + n0 + tx * 4] = o;
  }
}

extern "C" void kernel_launch(void* const* d_in, const int* in_sizes, int n_in,
                              void* d_out, int out_size, void* d_ws,
                              size_t ws_size, hipStream_t stream) {
  const float* x = (const float*)d_in[0];       // [2,64,48,512]
  const float* w_qkv = (const float*)d_in[1];   // [512,1536]
  const float* w_out = (const float*)d_in[2];   // [512,512]
  const float* rrow = (const float*)d_in[3];    // [127,8]
  const float* rcol = (const float*)d_in[4];    // [95,8]
  float* out = (float*)d_out;                   // [6144,512]

  const size_t QSZ = (size_t)2 * NHEADS * S_TOK * 64;  // 3,145,728 elems
  unsigned short* Q = (unsigned short*)d_ws;
  unsigned short* K = Q + QSZ;
  unsigned short* V = K + QSZ;
  unsigned short* Vt = V + QSZ;

  // choose split by available workspace
  const size_t base_bytes = 4 * QSZ * sizeof(unsigned short);
  const size_t per_split = (size_t)16 * S_TOK * 64 * 4 + (size_t)16 * S_TOK * 8;
  int nsplit = (ws_size >= base_bytes + 4 * per_split) ? 4 : 2;

  float* Opart = (float*)(Vt + QSZ);
  float2* Ml = (float2*)(Opart + (size_t)nsplit * 16 * S_TOK * 64);

  ga_qkv_gemm<<<dim3(96, 24), 256, 0, stream>>>(x, w_qkv, Q, K, V);
  ga_vtrans<<<dim3(48, 16), 256, 0, stream>>>(V, Vt);
  ga_attn_mfma<<<dim3(48, 16, nsplit), 256, 0, stream>>>(
      Q, K, Vt, rrow, rcol, Opart, Ml, 48 / nsplit);
  if (nsplit == 4)
    ga_out_gemm_combine<4><<<dim3(96, 8), 256, 0, stream>>>(Opart, Ml, w_out, out);
  else
    ga_out_gemm_combine<2><<<dim3(96, 8), 256, 0, stream>>>(Opart, Ml, w_out, out);
}

// Round 5
// 447.959 us; speedup vs baseline: 1.0108x; 1.0108x over previous
//
#include <hip/hip_runtime.h>

#define S_TOK 3072   // 64*48
#define NHEADS 8

typedef __attribute__((ext_vector_type(8))) short short8;
typedef __attribute__((ext_vector_type(4))) float floatx4;
typedef __attribute__((ext_vector_type(4))) unsigned short ushortx4;

__device__ __forceinline__ unsigned short f2bf(float f) {
  union { float f; unsigned u; } v; v.f = f;
  unsigned r = v.u + 0x7fffu + ((v.u >> 16) & 1u);   // RTN-even
  return (unsigned short)(r >> 16);
}

// ---------------- Pass A: QKV projection (f32 math, bf16 out) ----------------
// X [6144][512] @ W [512][1536] -> Q (pre-scaled by 1/8*log2e), K, V [bh][s][64]
__global__ __launch_bounds__(256) void ga_qkv_gemm(
    const float* __restrict__ X, const float* __restrict__ W,
    unsigned short* __restrict__ Q, unsigned short* __restrict__ K,
    unsigned short* __restrict__ V) {
  const int tid = threadIdx.x;
  const int ty = tid >> 4, tx = tid & 15;
  const int m0 = blockIdx.x * 64;
  const int n0 = blockIdx.y * 64;
  __shared__ float As[16][68];   // [k][m]
  __shared__ float Bs[16][68];   // [k][n]
  float acc[4][4] = {};
  const int lm = tid >> 2;   // 0..63
  const int lk4 = tid & 3;   // 0..3
  const int bk = tid >> 4;   // 0..15
  const int bn4 = tid & 15;  // 0..15
  for (int k0 = 0; k0 < 512; k0 += 16) {
    float4 a = *(const float4*)&X[(size_t)(m0 + lm) * 512 + k0 + lk4 * 4];
    As[lk4 * 4 + 0][lm] = a.x;
    As[lk4 * 4 + 1][lm] = a.y;
    As[lk4 * 4 + 2][lm] = a.z;
    As[lk4 * 4 + 3][lm] = a.w;
    *(float4*)&Bs[bk][bn4 * 4] =
        *(const float4*)&W[(size_t)(k0 + bk) * 1536 + n0 + bn4 * 4];
    __syncthreads();
#pragma unroll
    for (int kk = 0; kk < 16; ++kk) {
      float4 av = *(const float4*)&As[kk][ty * 4];
      float4 bv = *(const float4*)&Bs[kk][tx * 4];
      float aa[4] = {av.x, av.y, av.z, av.w};
      float bb[4] = {bv.x, bv.y, bv.z, bv.w};
#pragma unroll
      for (int i = 0; i < 4; ++i)
#pragma unroll
        for (int j = 0; j < 4; ++j)
          acc[i][j] = fmaf(aa[i], bb[j], acc[i][j]);
    }
    __syncthreads();
  }
  const int which = n0 >> 9;        // 0=Q 1=K 2=V
  const int h = (n0 >> 6) & 7;
  const int b = m0 / S_TOK;
  const int s0 = m0 % S_TOK;
  const int bh = b * NHEADS + h;
  unsigned short* dst =
      ((which == 0) ? Q : (which == 1) ? K : V) + (size_t)bh * S_TOK * 64;
  const float qscale = (which == 0) ? 0.18033688f : 1.0f;  // 1/8 * log2(e)
#pragma unroll
  for (int i = 0; i < 4; ++i) {
    ushortx4 o = {f2bf(acc[i][0] * qscale), f2bf(acc[i][1] * qscale),
                  f2bf(acc[i][2] * qscale), f2bf(acc[i][3] * qscale)};
    *(ushortx4*)&dst[(size_t)(s0 + ty * 4 + i) * 64 + tx * 4] = o;
  }
}

// ---------------- Pass A2: V transpose -> Vt [bh][d][s] ----------------
__global__ __launch_bounds__(256) void ga_vtrans(
    const unsigned short* __restrict__ V, unsigned short* __restrict__ Vt) {
  const int t = threadIdx.x;
  const int s0 = blockIdx.x * 64;
  const int bh = blockIdx.y;
  __shared__ unsigned short Ts[64][68];
  const unsigned short* vp = V + ((size_t)bh * S_TOK + s0) * 64;
#pragma unroll
  for (int it = 0; it < 2; ++it) {
    int s = it * 32 + (t >> 3);
    int d8 = t & 7;
    short8 v = *(const short8*)&vp[(size_t)s * 64 + d8 * 8];
    ushortx4 lo = {(unsigned short)v[0], (unsigned short)v[1],
                   (unsigned short)v[2], (unsigned short)v[3]};
    ushortx4 hi = {(unsigned short)v[4], (unsigned short)v[5],
                   (unsigned short)v[6], (unsigned short)v[7]};
    *(ushortx4*)&Ts[s][d8 * 8] = lo;
    *(ushortx4*)&Ts[s][d8 * 8 + 4] = hi;
  }
  __syncthreads();
  const int w = t >> 6, l = t & 63;
  unsigned short* dst = Vt + (size_t)bh * 64 * S_TOK + s0;
#pragma unroll
  for (int dd = 0; dd < 16; ++dd) {
    int d = w * 16 + dd;
    dst[(size_t)d * S_TOK + l] = Ts[l][d];
  }
}

// ------- Pass B: swapped-QK^T 16x16 MFMA attention, fixed-M softmax ---------
// grid (48 qblocks of 64, 16 bh, nsplit); block 256 = 4 waves x 16 q-rows.
// S^T = mfma(K, Q): C-col (lane&15) = query, C-row (g*4+r) = key-local.
// K-block = 192 = lcm(64-key mfma rows, 48): kr/kc offsets compile-time;
// all ctab bias values preloaded into 12 registers; rtab 4 loads/block.
// p = exp2(s + bias - 12) (scores bounded); l lane-local, reduced at end.
__global__ __launch_bounds__(256) void ga_attn16(
    const unsigned short* __restrict__ Q, const unsigned short* __restrict__ K,
    const unsigned short* __restrict__ Vt, const float* __restrict__ rowtab,
    const float* __restrict__ coltab, float* __restrict__ Opart,
    float* __restrict__ Lpart, int blocks_per_split) {
  const int tid = threadIdx.x;
  const int w = tid >> 6;
  const int l = tid & 63;
  const int g = l >> 4;     // lane group 0..3
  const int ln = l & 15;    // lane 0..15 (= query col in C layout)
  const int bh = blockIdx.y;
  const int sp = blockIdx.z;
  const int h = bh & 7;
  const int q0 = blockIdx.x * 64 + w * 16;

  __shared__ float rtab[127];
  __shared__ float ctab[95];
  __shared__ unsigned int Pw[4][256];  // per-wave 16q x 16 bf16x2-words
  for (int i = tid; i < 127; i += 256) rtab[i] = rowtab[i * 8 + h] * 1.44269504f;
  for (int i = tid; i < 95; i += 256) ctab[i] = coltab[i * 8 + h] * 1.44269504f;
  __syncthreads();

  const unsigned short* Qp = Q + (size_t)bh * S_TOK * 64;
  const unsigned short* Kp = K + (size_t)bh * S_TOK * 64;
  const unsigned short* Vp = Vt + (size_t)bh * 64 * S_TOK;

  const int q = q0 + ln;           // this lane's query
  const int qr = q / 48;
  const int qc = q - qr * 48;

  // Q B-frag: lane holds Q[q][d = c*32 + g*8 + j]  (same pattern as R2/R3)
  short8 qf0 = *(const short8*)&Qp[(size_t)q * 64 + g * 8];
  short8 qf1 = *(const short8*)&Qp[(size_t)q * 64 + 32 + g * 8];

  // ctab bias registers: kc = 16*m + g*4 + r (m = kt%3) -> 12 values, loop-invariant
  float ctr[3][4];
  {
    const float* cb = &ctab[qc - g * 4 + 47];
#pragma unroll
    for (int m = 0; m < 3; ++m)
#pragma unroll
      for (int r = 0; r < 4; ++r) ctr[m][r] = cb[-(16 * m + r)];
  }

  floatx4 o_acc[4];
#pragma unroll
  for (int dt = 0; dt < 4; ++dt)
#pragma unroll
    for (int r = 0; r < 4; ++r) o_acc[dt][r] = 0.f;
  float lsum = 0.f;

  const int kb0 = sp * blocks_per_split;
  for (int kb = kb0; kb < kb0 + blocks_per_split; ++kb) {
    const int k0 = kb * 192;
    // rtab values for the 4 grid-rows this block spans (kr = 4kb + wrap), -M folded
    float rt[4];
#pragma unroll
    for (int ww = 0; ww < 4; ++ww)
      rt[ww] = rtab[qr + 63 - 4 * kb - ww] - 12.0f;
#pragma unroll
    for (int kt = 0; kt < 12; ++kt) {
      // ---- S^T = K Q^T : A = K rows (keys kt*16+ln), k-dim = d (2 chunks)
      const unsigned short* kp = &Kp[(size_t)(k0 + kt * 16 + ln) * 64 + g * 8];
      short8 kf0 = *(const short8*)kp;
      short8 kf1 = *(const short8*)(kp + 32);
      floatx4 s = {0.f, 0.f, 0.f, 0.f};
      s = __builtin_amdgcn_mfma_f32_16x16x32_bf16(kf0, qf0, s, 0, 0, 0);
      s = __builtin_amdgcn_mfma_f32_16x16x32_bf16(kf1, qf1, s, 0, 0, 0);
      // ---- p = exp2(s + rt + ct); key = k0 + kt*16 + g*4 + r
      const float rtw = rt[kt / 3];
      float e0 = __builtin_amdgcn_exp2f(s[0] + rtw + ctr[kt % 3][0]);
      float e1 = __builtin_amdgcn_exp2f(s[1] + rtw + ctr[kt % 3][1]);
      float e2 = __builtin_amdgcn_exp2f(s[2] + rtw + ctr[kt % 3][2]);
      float e3 = __builtin_amdgcn_exp2f(s[3] + rtw + ctr[kt % 3][3]);
      lsum += (e0 + e1) + (e2 + e3);
      // ---- pack key-pairs (consecutive) into bf16x2 words -> per-wave LDS
      uint2 pwd;
      pwd.x = (unsigned)f2bf(e0) | ((unsigned)f2bf(e1) << 16);
      pwd.y = (unsigned)f2bf(e2) | ((unsigned)f2bf(e3) << 16);
      const int wb = (kt & 1) * 8 + g * 2;  // word index (local key / 2)
      *(uint2*)&Pw[w][(ln * 16 + wb) ^ ((ln & 3) << 2)] = pwd;
      if (kt & 1) {
        // ---- 32-key chunk complete: O += P V
        const int cbase = k0 + (kt - 1) * 16;
        short8 pf =
            *(const short8*)&Pw[w][(ln * 16 + g * 4) ^ ((ln & 3) << 2)];
#pragma unroll
        for (int dt = 0; dt < 4; ++dt) {
          short8 vf = *(const short8*)&Vp[(size_t)(dt * 16 + ln) * S_TOK +
                                          cbase + g * 8];
          o_acc[dt] =
              __builtin_amdgcn_mfma_f32_16x16x32_bf16(pf, vf, o_acc[dt], 0, 0, 0);
        }
      }
    }
  }
  // ---- epilogue: reduce l across the 4 lane-groups (same query ln)
  float lt = lsum + __shfl_xor(lsum, 16);
  lt += __shfl_xor(lt, 32);
  const size_t rowbase = (size_t)(sp * 16 + bh) * S_TOK;
  if (l < 16) Lpart[rowbase + q] = lt;
  // o_acc: row (query) = g*4 + r, col (d) = dt*16 + ln
#pragma unroll
  for (int dt = 0; dt < 4; ++dt)
#pragma unroll
    for (int r = 0; r < 4; ++r)
      Opart[(rowbase + q0 + g * 4 + r) * 64 + dt * 16 + ln] = o_acc[dt][r];
}

// ------- Pass C: combine split-K partials fused into output projection -------
template <int NS>
__global__ __launch_bounds__(256) void ga_out_gemm_combine(
    const float* __restrict__ Opart, const float* __restrict__ Lpart,
    const float* __restrict__ W, float* __restrict__ Out) {
  const int tid = threadIdx.x;
  const int ty = tid >> 4, tx = tid & 15;
  const int m0 = blockIdx.x * 64;
  const int n0 = blockIdx.y * 64;
  __shared__ float As[16][68];
  __shared__ float Bs[16][68];
  float acc[4][4] = {};
  const int lm = tid >> 2, lk4 = tid & 3;
  const int bk = tid >> 4, bn4 = tid & 15;
  const int m = m0 + lm;
  const int b = m / S_TOK;
  const int q = m - b * S_TOK;
  for (int k0 = 0; k0 < 512; k0 += 16) {
    // --- A stage: plain-add split-K combine + l-normalize
    {
      const int kk = k0 + lk4 * 4;
      const int h = kk >> 6;
      const int d = kk & 63;
      const int bh = b * 8 + h;
      float ax = 0.f, ay = 0.f, az = 0.f, aw = 0.f, lsum = 0.f;
#pragma unroll
      for (int s = 0; s < NS; ++s) {
        const size_t row = (size_t)(s * 16 + bh) * S_TOK + q;
        const float4 o = *(const float4*)&Opart[row * 64 + d];
        ax += o.x; ay += o.y; az += o.z; aw += o.w;
        lsum += Lpart[row];
      }
      const float inv = 1.0f / lsum;
      As[lk4 * 4 + 0][lm] = ax * inv;
      As[lk4 * 4 + 1][lm] = ay * inv;
      As[lk4 * 4 + 2][lm] = az * inv;
      As[lk4 * 4 + 3][lm] = aw * inv;
    }
    *(float4*)&Bs[bk][bn4 * 4] =
        *(const float4*)&W[(size_t)(k0 + bk) * 512 + n0 + bn4 * 4];
    __syncthreads();
#pragma unroll
    for (int kk = 0; kk < 16; ++kk) {
      float4 av = *(const float4*)&As[kk][ty * 4];
      float4 bv = *(const float4*)&Bs[kk][tx * 4];
      float aa[4] = {av.x, av.y, av.z, av.w};
      float bb[4] = {bv.x, bv.y, bv.z, bv.w};
#pragma unroll
      for (int i = 0; i < 4; ++i)
#pragma unroll
        for (int j = 0; j < 4; ++j)
          acc[i][j] = fmaf(aa[i], bb[j], acc[i][j]);
    }
    __syncthreads();
  }
#pragma unroll
  for (int i = 0; i < 4; ++i) {
    float4 o = make_float4(acc[i][0], acc[i][1], acc[i][2], acc[i][3]);
    *(float4*)&Out[(size_t)(m0 + ty * 4 + i) * 512 + n0 + tx * 4] = o;
  }
}

extern "C" void kernel_launch(void* const* d_in, const int* in_sizes, int n_in,
                              void* d_out, int out_size, void* d_ws,
                              size_t ws_size, hipStream_t stream) {
  const float* x = (const float*)d_in[0];       // [2,64,48,512]
  const float* w_qkv = (const float*)d_in[1];   // [512,1536]
  const float* w_out = (const float*)d_in[2];   // [512,512]
  const float* rrow = (const float*)d_in[3];    // [127,8]
  const float* rcol = (const float*)d_in[4];    // [95,8]
  float* out = (float*)d_out;                   // [6144,512]

  const size_t QSZ = (size_t)2 * NHEADS * S_TOK * 64;  // 3,145,728 elems
  unsigned short* Q = (unsigned short*)d_ws;
  unsigned short* K = Q + QSZ;
  unsigned short* V = K + QSZ;
  unsigned short* Vt = V + QSZ;

  const size_t base_bytes = 4 * QSZ * sizeof(unsigned short);
  const size_t per_split =
      (size_t)16 * S_TOK * 64 * 4 + (size_t)16 * S_TOK * 4;  // Opart + Lpart
  int nsplit = (ws_size >= base_bytes + 4 * per_split) ? 4 : 2;

  float* Opart = (float*)(Vt + QSZ);
  float* Lpart = Opart + (size_t)nsplit * 16 * S_TOK * 64;

  ga_qkv_gemm<<<dim3(96, 24), 256, 0, stream>>>(x, w_qkv, Q, K, V);
  ga_vtrans<<<dim3(48, 16), 256, 0, stream>>>(V, Vt);
  ga_attn16<<<dim3(48, 16, nsplit), 256, 0, stream>>>(
      Q, K, Vt, rrow, rcol, Opart, Lpart, 16 / nsplit);
  if (nsplit == 4)
    ga_out_gemm_combine<4><<<dim3(96, 8), 256, 0, stream>>>(Opart, Lpart, w_out, out);
  else
    ga_out_gemm_combine<2><<<dim3(96, 8), 256, 0, stream>>>(Opart, Lpart, w_out, out);
}

// Round 6
// 275.987 us; speedup vs baseline: 1.6406x; 1.6231x over previous
//
#include <hip/hip_runtime.h>

#define S_TOK 3072   // 64*48
#define NHEADS 8

typedef __attribute__((ext_vector_type(8))) short short8;
typedef __attribute__((ext_vector_type(4))) float floatx4;
typedef __attribute__((ext_vector_type(4))) unsigned short ushortx4;

__device__ __forceinline__ unsigned short f2bf(float f) {
  union { float f; unsigned u; } v; v.f = f;
  unsigned r = v.u + 0x7fffu + ((v.u >> 16) & 1u);   // RTN-even
  return (unsigned short)(r >> 16);
}

__device__ __forceinline__ void gload16(const void* g, void* l) {
  __builtin_amdgcn_global_load_lds(
      (const __attribute__((address_space(1))) unsigned int*)g,
      (__attribute__((address_space(3))) unsigned int*)l, 16, 0, 0);
}

// ---------------- Pass A: QKV projection (f32 math, bf16 out) ----------------
// X [6144][512] @ W [512][1536] -> Q (pre-scaled by 1/8*log2e), K (row-swizzled),
// V plain row-major; all [bh][s][64].
__global__ __launch_bounds__(256) void ga_qkv_gemm(
    const float* __restrict__ X, const float* __restrict__ W,
    unsigned short* __restrict__ Q, unsigned short* __restrict__ K,
    unsigned short* __restrict__ V) {
  const int tid = threadIdx.x;
  const int ty = tid >> 4, tx = tid & 15;
  const int m0 = blockIdx.x * 64;
  const int n0 = blockIdx.y * 64;
  __shared__ float As[16][68];   // [k][m]
  __shared__ float Bs[16][68];   // [k][n]
  float acc[4][4] = {};
  const int lm = tid >> 2;   // 0..63
  const int lk4 = tid & 3;   // 0..3
  const int bk = tid >> 4;   // 0..15
  const int bn4 = tid & 15;  // 0..15
  for (int k0 = 0; k0 < 512; k0 += 16) {
    float4 a = *(const float4*)&X[(size_t)(m0 + lm) * 512 + k0 + lk4 * 4];
    As[lk4 * 4 + 0][lm] = a.x;
    As[lk4 * 4 + 1][lm] = a.y;
    As[lk4 * 4 + 2][lm] = a.z;
    As[lk4 * 4 + 3][lm] = a.w;
    *(float4*)&Bs[bk][bn4 * 4] =
        *(const float4*)&W[(size_t)(k0 + bk) * 1536 + n0 + bn4 * 4];
    __syncthreads();
#pragma unroll
    for (int kk = 0; kk < 16; ++kk) {
      float4 av = *(const float4*)&As[kk][ty * 4];
      float4 bv = *(const float4*)&Bs[kk][tx * 4];
      float aa[4] = {av.x, av.y, av.z, av.w};
      float bb[4] = {bv.x, bv.y, bv.z, bv.w};
#pragma unroll
      for (int i = 0; i < 4; ++i)
#pragma unroll
        for (int j = 0; j < 4; ++j)
          acc[i][j] = fmaf(aa[i], bb[j], acc[i][j]);
    }
    __syncthreads();
  }
  const int which = n0 >> 9;        // 0=Q 1=K 2=V
  const int h = (n0 >> 6) & 7;
  const int b = m0 / S_TOK;
  const int s0 = m0 % S_TOK;
  const int bh = b * NHEADS + h;
  unsigned short* dst =
      ((which == 0) ? Q : (which == 1) ? K : V) + (size_t)bh * S_TOK * 64;
  const float qscale = (which == 0) ? 0.18033688f : 1.0f;  // 1/8 * log2(e)
#pragma unroll
  for (int i = 0; i < 4; ++i) {
    ushortx4 o = {f2bf(acc[i][0] * qscale), f2bf(acc[i][1] * qscale),
                  f2bf(acc[i][2] * qscale), f2bf(acc[i][3] * qscale)};
    const int s = s0 + ty * 4 + i;
    size_t idx = (size_t)s * 64 + tx * 4;
    if (which == 1) idx ^= (size_t)((s & 7) << 3);  // K pre-swizzle (8-u16 granule)
    *(ushortx4*)&dst[idx] = o;
  }
}

// ---- Pass A2: V -> tiled/transposed/pre-swizzled Vt2 [bh][32 tiles][64 d][128 k] ----
// tile-local u16 addr for value V[k][d] is (d*128 + k) ^ ((d&7)<<3); k>=96 -> 0 pad.
__global__ __launch_bounds__(256) void ga_vtrans(
    const unsigned short* __restrict__ V, unsigned short* __restrict__ Vt2) {
  const int t = threadIdx.x;
  const int tile = blockIdx.x;
  const int bh = blockIdx.y;
  __shared__ unsigned short Ts[96][72];
  const unsigned short* vp = V + ((size_t)bh * S_TOK + tile * 96) * 64;
#pragma unroll
  for (int it = 0; it < 3; ++it) {
    int c = it * 256 + t;     // 768 chunks of 8 u16
    int s = c >> 3, d8 = c & 7;
    short8 v = *(const short8*)&vp[(size_t)s * 64 + d8 * 8];
    *(short8*)&Ts[s][d8 * 8] = v;
  }
  __syncthreads();
  unsigned short* op = Vt2 + ((size_t)bh * 32 + tile) * 8192;
#pragma unroll
  for (int it = 0; it < 4; ++it) {
    int c2 = it * 256 + t;    // 1024 chunks
    int a = c2 * 8;           // u16 addr in tile
    int d = a >> 7;
    int kb = (a & 127) ^ ((d & 7) << 3);   // multiple of 8
    short8 o;
    if (kb < 96) {
#pragma unroll
      for (int j = 0; j < 8; ++j) o[j] = (short)Ts[kb + j][d];
    } else {
#pragma unroll
      for (int j = 0; j < 8; ++j) o[j] = 0;
    }
    *(short8*)&op[a] = o;
  }
}

// ------- Pass B: swapped-QK^T 16x16 MFMA attention, LDS-staged K/V ----------
// grid (24 qblocks of 128, 16 bh, nsplit); block 256 = 4 waves x 32 q-rows.
// Per 96-key tile: stage K (12KB) + V (16KB) via global_load_lds (pre-swizzled
// in global), then frags via conflict-free swizzled ds_read_b128.
__global__ __launch_bounds__(256) void ga_attn16(
    const unsigned short* __restrict__ Q, const unsigned short* __restrict__ Kg,
    const unsigned short* __restrict__ Vt2, const float* __restrict__ rowtab,
    const float* __restrict__ coltab, float* __restrict__ Opart,
    float* __restrict__ Lpart, int tiles_per_split) {
  const int tid = threadIdx.x;
  const int w = tid >> 6;
  const int l = tid & 63;
  const int g = l >> 4;     // lane group 0..3
  const int ln = l & 15;    // query col in S^T C-layout
  const int bh = blockIdx.y;
  const int sp = blockIdx.z;
  const int h = bh & 7;
  const int q0 = blockIdx.x * 128 + w * 32;

  __shared__ float rtab[127];
  __shared__ float ctab[95];
  __shared__ unsigned short Klds[6144];   // [96 keys][64 d] swizzled, 12KB
  __shared__ unsigned short Vlds[8192];   // [64 d][128 k] swizzled, 16KB
  __shared__ unsigned int Pw[4][512];     // per-wave P chunk (2 q-subtiles)
  for (int i = tid; i < 127; i += 256) rtab[i] = rowtab[i * 8 + h] * 1.44269504f;
  for (int i = tid; i < 95; i += 256) ctab[i] = coltab[i * 8 + h] * 1.44269504f;
  __syncthreads();

  const unsigned short* Qp = Q + (size_t)bh * S_TOK * 64;
  const unsigned short* Kp = Kg + (size_t)bh * S_TOK * 64;
  const unsigned short* Vp = Vt2 + (size_t)bh * 32 * 8192;

  // per-sub-tile query state
  int qr[2], qc[2];
  short8 qf[2][2];
  float ctr[2][3][4];
#pragma unroll
  for (int u = 0; u < 2; ++u) {
    const int q = q0 + u * 16 + ln;
    qr[u] = q / 48;
    qc[u] = q - qr[u] * 48;
    qf[u][0] = *(const short8*)&Qp[(size_t)q * 64 + g * 8];
    qf[u][1] = *(const short8*)&Qp[(size_t)q * 64 + 32 + g * 8];
    const float* cb = &ctab[qc[u] - g * 4 + 47];
#pragma unroll
    for (int m = 0; m < 3; ++m)
#pragma unroll
      for (int r = 0; r < 4; ++r) ctr[u][m][r] = cb[-(16 * m + r)];
  }

  floatx4 o_acc[2][4];
#pragma unroll
  for (int u = 0; u < 2; ++u)
#pragma unroll
    for (int dt = 0; dt < 4; ++dt)
#pragma unroll
      for (int r = 0; r < 4; ++r) o_acc[u][dt][r] = 0.f;
  float lsum[2] = {0.f, 0.f};

  const int t0 = sp * tiles_per_split;
  for (int t = t0; t < t0 + tiles_per_split; ++t) {
    __syncthreads();  // previous tile fully consumed
    {   // stage K 12KB + V 16KB, coalesced, shared by all 4 waves
      const char* kg = (const char*)(Kp + (size_t)t * 96 * 64);
      const char* vg = (const char*)(Vp + (size_t)t * 8192);
#pragma unroll
      for (int i = 0; i < 3; ++i) {
        const int off = w * 3072 + i * 1024;
        gload16(kg + off + l * 16, (char*)Klds + off);
      }
#pragma unroll
      for (int i = 0; i < 4; ++i) {
        const int off = w * 4096 + i * 1024;
        gload16(vg + off + l * 16, (char*)Vlds + off);
      }
      asm volatile("s_waitcnt vmcnt(0)" ::: "memory");
      __syncthreads();
    }
    float rt[2][2];
#pragma unroll
    for (int u = 0; u < 2; ++u) {
      rt[u][0] = rtab[qr[u] + 63 - 2 * t] - 12.0f;
      rt[u][1] = rtab[qr[u] + 62 - 2 * t] - 12.0f;
    }
    const int swz = (ln & 7) << 3;
#pragma unroll
    for (int kc32 = 0; kc32 < 3; ++kc32) {
#pragma unroll
      for (int kh = 0; kh < 2; ++kh) {
        const int kt = kc32 * 2 + kh;
        const int rb = (kt * 16 + ln) * 64;
        short8 kf0 = *(const short8*)&Klds[rb + ((g * 8) ^ swz)];
        short8 kf1 = *(const short8*)&Klds[rb + ((32 + g * 8) ^ swz)];
        const int m = kt % 3, wrap = kt / 3;
#pragma unroll
        for (int u = 0; u < 2; ++u) {
          floatx4 s = {0.f, 0.f, 0.f, 0.f};
          s = __builtin_amdgcn_mfma_f32_16x16x32_bf16(kf0, qf[u][0], s, 0, 0, 0);
          s = __builtin_amdgcn_mfma_f32_16x16x32_bf16(kf1, qf[u][1], s, 0, 0, 0);
          const float rtw = rt[u][wrap];
          float e0 = __builtin_amdgcn_exp2f(s[0] + rtw + ctr[u][m][0]);
          float e1 = __builtin_amdgcn_exp2f(s[1] + rtw + ctr[u][m][1]);
          float e2 = __builtin_amdgcn_exp2f(s[2] + rtw + ctr[u][m][2]);
          float e3 = __builtin_amdgcn_exp2f(s[3] + rtw + ctr[u][m][3]);
          lsum[u] += (e0 + e1) + (e2 + e3);
          uint2 pwd;
          pwd.x = (unsigned)f2bf(e0) | ((unsigned)f2bf(e1) << 16);
          pwd.y = (unsigned)f2bf(e2) | ((unsigned)f2bf(e3) << 16);
          *(uint2*)&Pw[w][u * 256 +
                          ((ln * 16 + kh * 8 + g * 2) ^ ((ln & 3) << 2))] = pwd;
        }
      }
      // ---- O += P V for this 32-key chunk (V-frags shared across sub-tiles)
      short8 pf[2];
#pragma unroll
      for (int u = 0; u < 2; ++u)
        pf[u] = *(const short8*)&Pw[w][u * 256 +
                                       ((ln * 16 + g * 4) ^ ((ln & 3) << 2))];
#pragma unroll
      for (int dt = 0; dt < 4; ++dt) {
        const int vrow = dt * 16 + ln;
        short8 vf = *(const short8*)&Vlds[vrow * 128 +
                                          ((kc32 * 32 + g * 8) ^ swz)];
        o_acc[0][dt] =
            __builtin_amdgcn_mfma_f32_16x16x32_bf16(pf[0], vf, o_acc[0][dt], 0, 0, 0);
        o_acc[1][dt] =
            __builtin_amdgcn_mfma_f32_16x16x32_bf16(pf[1], vf, o_acc[1][dt], 0, 0, 0);
      }
    }
  }
  // ---- epilogue
  const size_t rowbase = (size_t)(sp * 16 + bh) * S_TOK;
#pragma unroll
  for (int u = 0; u < 2; ++u) {
    float lt = lsum[u] + __shfl_xor(lsum[u], 16);
    lt += __shfl_xor(lt, 32);
    if (l < 16) Lpart[rowbase + q0 + u * 16 + ln] = lt;
#pragma unroll
    for (int dt = 0; dt < 4; ++dt)
#pragma unroll
      for (int r = 0; r < 4; ++r)
        Opart[(rowbase + q0 + u * 16 + g * 4 + r) * 64 + dt * 16 + ln] =
            o_acc[u][dt][r];
  }
}

// ------- Pass C: combine split-K partials fused into output projection -------
template <int NS>
__global__ __launch_bounds__(256) void ga_out_gemm_combine(
    const float* __restrict__ Opart, const float* __restrict__ Lpart,
    const float* __restrict__ W, float* __restrict__ Out) {
  const int tid = threadIdx.x;
  const int ty = tid >> 4, tx = tid & 15;
  const int m0 = blockIdx.x * 64;
  const int n0 = blockIdx.y * 64;
  __shared__ float As[16][68];
  __shared__ float Bs[16][68];
  float acc[4][4] = {};
  const int lm = tid >> 2, lk4 = tid & 3;
  const int bk = tid >> 4, bn4 = tid & 15;
  const int m = m0 + lm;
  const int b = m / S_TOK;
  const int q = m - b * S_TOK;
  for (int k0 = 0; k0 < 512; k0 += 16) {
    {
      const int kk = k0 + lk4 * 4;
      const int h = kk >> 6;
      const int d = kk & 63;
      const int bh = b * 8 + h;
      float ax = 0.f, ay = 0.f, az = 0.f, aw = 0.f, lsum = 0.f;
#pragma unroll
      for (int s = 0; s < NS; ++s) {
        const size_t row = (size_t)(s * 16 + bh) * S_TOK + q;
        const float4 o = *(const float4*)&Opart[row * 64 + d];
        ax += o.x; ay += o.y; az += o.z; aw += o.w;
        lsum += Lpart[row];
      }
      const float inv = 1.0f / lsum;
      As[lk4 * 4 + 0][lm] = ax * inv;
      As[lk4 * 4 + 1][lm] = ay * inv;
      As[lk4 * 4 + 2][lm] = az * inv;
      As[lk4 * 4 + 3][lm] = aw * inv;
    }
    *(float4*)&Bs[bk][bn4 * 4] =
        *(const float4*)&W[(size_t)(k0 + bk) * 512 + n0 + bn4 * 4];
    __syncthreads();
#pragma unroll
    for (int kk = 0; kk < 16; ++kk) {
      float4 av = *(const float4*)&As[kk][ty * 4];
      float4 bv = *(const float4*)&Bs[kk][tx * 4];
      float aa[4] = {av.x, av.y, av.z, av.w};
      float bb[4] = {bv.x, bv.y, bv.z, bv.w};
#pragma unroll
      for (int i = 0; i < 4; ++i)
#pragma unroll
        for (int j = 0; j < 4; ++j)
          acc[i][j] = fmaf(aa[i], bb[j], acc[i][j]);
    }
    __syncthreads();
  }
#pragma unroll
  for (int i = 0; i < 4; ++i) {
    float4 o = make_float4(acc[i][0], acc[i][1], acc[i][2], acc[i][3]);
    *(float4*)&Out[(size_t)(m0 + ty * 4 + i) * 512 + n0 + tx * 4] = o;
  }
}

extern "C" void kernel_launch(void* const* d_in, const int* in_sizes, int n_in,
                              void* d_out, int out_size, void* d_ws,
                              size_t ws_size, hipStream_t stream) {
  const float* x = (const float*)d_in[0];       // [2,64,48,512]
  const float* w_qkv = (const float*)d_in[1];   // [512,1536]
  const float* w_out = (const float*)d_in[2];   // [512,512]
  const float* rrow = (const float*)d_in[3];    // [127,8]
  const float* rcol = (const float*)d_in[4];    // [95,8]
  float* out = (float*)d_out;                   // [6144,512]

  const size_t QSZ = (size_t)2 * NHEADS * S_TOK * 64;    // 3,145,728 elems
  const size_t VT2SZ = (size_t)2 * NHEADS * 32 * 8192;   // 4,194,304 elems
  unsigned short* Q = (unsigned short*)d_ws;
  unsigned short* K = Q + QSZ;
  unsigned short* V = K + QSZ;
  unsigned short* Vt2 = V + QSZ;

  const size_t base_bytes = (3 * QSZ + VT2SZ) * sizeof(unsigned short);
  const size_t per_split =
      (size_t)16 * S_TOK * 64 * 4 + (size_t)16 * S_TOK * 4;  // Opart + Lpart
  int nsplit = (ws_size >= base_bytes + 4 * per_split) ? 4 : 2;

  float* Opart = (float*)(Vt2 + VT2SZ);
  float* Lpart = Opart + (size_t)nsplit * 16 * S_TOK * 64;

  ga_qkv_gemm<<<dim3(96, 24), 256, 0, stream>>>(x, w_qkv, Q, K, V);
  ga_vtrans<<<dim3(32, 16), 256, 0, stream>>>(V, Vt2);
  ga_attn16<<<dim3(24, 16, nsplit), 256, 0, stream>>>(
      Q, K, Vt2, rrow, rcol, Opart, Lpart, 32 / nsplit);
  if (nsplit == 4)
    ga_out_gemm_combine<4><<<dim3(96, 8), 256, 0, stream>>>(Opart, Lpart, w_out, out);
  else
    ga_out_gemm_combine<2><<<dim3(96, 8), 256, 0, stream>>>(Opart, Lpart, w_out, out);
}

// Round 7
// 162.339 us; speedup vs baseline: 2.7891x; 1.7001x over previous
//
#include <hip/hip_runtime.h>

#define S_TOK 3072   // 64*48
#define NHEADS 8

typedef __attribute__((ext_vector_type(8))) short short8;
typedef __attribute__((ext_vector_type(4))) float floatx4;
typedef __attribute__((ext_vector_type(4))) unsigned short ushortx4;

__device__ __forceinline__ unsigned short f2bf(float f) {
  union { float f; unsigned u; } v; v.f = f;
  unsigned r = v.u + 0x7fffu + ((v.u >> 16) & 1u);   // RTN-even
  return (unsigned short)(r >> 16);
}
__device__ __forceinline__ float bf2f(unsigned short h) {
  union { unsigned u; float f; } v; v.u = (unsigned)h << 16;
  return v.f;
}
__device__ __forceinline__ void gload16(const void* g, void* l) {
  __builtin_amdgcn_global_load_lds(
      (const __attribute__((address_space(1))) unsigned int*)g,
      (__attribute__((address_space(3))) unsigned int*)l, 16, 0, 0);
}

// ---- hi/lo convert of X (no transpose), swizzled within 64-col blocks ----
__global__ __launch_bounds__(256) void ga_conv_x(
    const float* __restrict__ X, unsigned short* __restrict__ xh,
    unsigned short* __restrict__ xl) {
  const int c = blockIdx.x * 256 + threadIdx.x;   // 393216 chunks of 8
  const int m = c >> 6;
  const int c8 = (c & 63) << 3;
  const float* src = X + (size_t)m * 512 + c8;
  float4 v0 = *(const float4*)src, v1 = *(const float4*)(src + 4);
  float vv[8] = {v0.x, v0.y, v0.z, v0.w, v1.x, v1.y, v1.z, v1.w};
  union { unsigned short s[8]; short8 v; } hh, ll;
#pragma unroll
  for (int e = 0; e < 8; ++e) {
    hh.s[e] = f2bf(vv[e]);
    ll.s[e] = f2bf(vv[e] - bf2f(hh.s[e]));
  }
  const size_t dst = (size_t)m * 512 + (c8 ^ ((m & 7) << 3));
  *(short8*)&xh[dst] = hh.v;
  *(short8*)&xl[dst] = ll.v;
}

// ---- hi/lo convert + transpose of W [K=512][N] -> wT [N][512], swizzled ----
__global__ __launch_bounds__(256) void ga_conv_wt(
    const float* __restrict__ W, unsigned short* __restrict__ th,
    unsigned short* __restrict__ tl, int N) {
  const int k0 = blockIdx.x * 64, n0 = blockIdx.y * 64;
  const int t = threadIdx.x;
  __shared__ float Ts[64][65];
#pragma unroll
  for (int i = 0; i < 4; ++i) {
    const int r = (t >> 4) + i * 16, c4 = (t & 15) * 4;
    float4 v = *(const float4*)&W[(size_t)(k0 + r) * N + n0 + c4];
    Ts[r][c4] = v.x; Ts[r][c4 + 1] = v.y; Ts[r][c4 + 2] = v.z; Ts[r][c4 + 3] = v.w;
  }
  __syncthreads();
#pragma unroll
  for (int j = 0; j < 2; ++j) {
    const int chunk = t * 2 + j;         // 512 chunks of 8
    const int nl = chunk >> 3, m8 = chunk & 7;
    const int n = n0 + nl;
    const int ks = (m8 * 8) ^ ((n & 7) << 3);
    union { unsigned short s[8]; short8 v; } hh, ll;
#pragma unroll
    for (int e = 0; e < 8; ++e) {
      float f = Ts[ks + e][nl];
      hh.s[e] = f2bf(f);
      ll.s[e] = f2bf(f - bf2f(hh.s[e]));
    }
    const size_t dst = (size_t)n * 512 + k0 + m8 * 8;
    *(short8*)&th[dst] = hh.v;
    *(short8*)&tl[dst] = ll.v;
  }
}

// ---- bf16x3 MFMA GEMM: C[m][n] = A[m][512] * B[512][n], A/B pre-split hi/lo,
// pre-swizzled, B stored transposed [n][512]. WHICH=0: QKV epilogue; 1: f32 out.
template <int BM, int BN, int WHICH>
__global__ __launch_bounds__(256, 2) void ga_mm3(
    const unsigned short* __restrict__ Ah, const unsigned short* __restrict__ Al,
    const unsigned short* __restrict__ Bh, const unsigned short* __restrict__ Bl,
    unsigned short* __restrict__ Qd, unsigned short* __restrict__ Kd,
    unsigned short* __restrict__ Vd, float* __restrict__ Out) {
  const int tid = threadIdx.x;
  const int w = tid >> 6, l = tid & 63;
  const int g = l >> 4, ln = l & 15;
  const int wm = w >> 1, wn = w & 1;
  const int m0 = blockIdx.x * BM;
  const int n0 = blockIdx.y * BN;
  constexpr int MI = BM / 32;
  constexpr int NI = BN / 32;
  __shared__ unsigned short Alds[2][BM * 64];
  __shared__ unsigned short Blds[2][BN * 64];
  floatx4 acc[MI][NI];
#pragma unroll
  for (int mi = 0; mi < MI; ++mi)
#pragma unroll
    for (int ni = 0; ni < NI; ++ni)
#pragma unroll
      for (int r = 0; r < 4; ++r) acc[mi][ni][r] = 0.f;

  for (int k0 = 0; k0 < 512; k0 += 64) {
    __syncthreads();
    // stage 4 tiles (rows: global stride 1024B, tile 128B)
    {
      constexpr int PWA = (BM * 128) / 4096;   // 1KB issues/wave, A tile
      constexpr int PWB = (BN * 128) / 4096;
      const char* ga_h = (const char*)(Ah + (size_t)m0 * 512 + k0);
      const char* ga_l = (const char*)(Al + (size_t)m0 * 512 + k0);
      const char* gb_h = (const char*)(Bh + (size_t)n0 * 512 + k0);
      const char* gb_l = (const char*)(Bl + (size_t)n0 * 512 + k0);
#pragma unroll
      for (int i = 0; i < PWA; ++i) {
        const int off = (w * PWA + i) * 1024;
        const int gb = ((off >> 7) + (l >> 3)) * 1024 + (l & 7) * 16;
        gload16(ga_h + gb, (char*)&Alds[0][0] + off);
        gload16(ga_l + gb, (char*)&Alds[1][0] + off);
      }
#pragma unroll
      for (int i = 0; i < PWB; ++i) {
        const int off = (w * PWB + i) * 1024;
        const int gb = ((off >> 7) + (l >> 3)) * 1024 + (l & 7) * 16;
        gload16(gb_h + gb, (char*)&Blds[0][0] + off);
        gload16(gb_l + gb, (char*)&Blds[1][0] + off);
      }
    }
    asm volatile("s_waitcnt vmcnt(0)" ::: "memory");
    __syncthreads();
#pragma unroll
    for (int kk = 0; kk < 64; kk += 32) {
      const int kbase = kk + g * 8;
      short8 ah[MI], al[MI], bh[NI], bl[NI];
#pragma unroll
      for (int mi = 0; mi < MI; ++mi) {
        const int row = wm * (BM / 2) + mi * 16 + ln;
        const int a = row * 64 + (kbase ^ ((row & 7) << 3));
        ah[mi] = *(const short8*)&Alds[0][a];
        al[mi] = *(const short8*)&Alds[1][a];
      }
#pragma unroll
      for (int ni = 0; ni < NI; ++ni) {
        const int row = wn * (BN / 2) + ni * 16 + ln;
        const int a = row * 64 + (kbase ^ ((row & 7) << 3));
        bh[ni] = *(const short8*)&Blds[0][a];
        bl[ni] = *(const short8*)&Blds[1][a];
      }
#pragma unroll
      for (int mi = 0; mi < MI; ++mi)
#pragma unroll
        for (int ni = 0; ni < NI; ++ni) {
          acc[mi][ni] = __builtin_amdgcn_mfma_f32_16x16x32_bf16(
              ah[mi], bh[ni], acc[mi][ni], 0, 0, 0);
          acc[mi][ni] = __builtin_amdgcn_mfma_f32_16x16x32_bf16(
              al[mi], bh[ni], acc[mi][ni], 0, 0, 0);
          acc[mi][ni] = __builtin_amdgcn_mfma_f32_16x16x32_bf16(
              ah[mi], bl[ni], acc[mi][ni], 0, 0, 0);
        }
    }
  }
  if constexpr (WHICH == 0) {
    const int b = m0 / S_TOK;
    const int s_base = (m0 % S_TOK) + wm * (BM / 2);
#pragma unroll
    for (int ni = 0; ni < NI; ++ni) {
      const int ng = n0 + wn * (BN / 2) + ni * 16;
      const int which = ng >> 9;
      const int h = (ng >> 6) & 7;
      const int d = (ng & 63) + ln;
      unsigned short* hp = (which == 0 ? Qd : which == 1 ? Kd : Vd) +
                           (size_t)(b * 8 + h) * S_TOK * 64;
      const float qs = (which == 0) ? 0.18033688f : 1.0f;  // 1/8*log2e
#pragma unroll
      for (int mi = 0; mi < MI; ++mi)
#pragma unroll
        for (int r = 0; r < 4; ++r) {
          const int s = s_base + mi * 16 + g * 4 + r;
          const size_t idx =
              (size_t)s * 64 + ((which == 1) ? (d ^ ((s & 7) << 3)) : d);
          hp[idx] = f2bf(acc[mi][ni][r] * qs);
        }
    }
  } else {
#pragma unroll
    for (int mi = 0; mi < MI; ++mi)
#pragma unroll
      for (int ni = 0; ni < NI; ++ni)
#pragma unroll
        for (int r = 0; r < 4; ++r)
          Out[(size_t)(m0 + wm * (BM / 2) + mi * 16 + g * 4 + r) * 512 + n0 +
              wn * (BN / 2) + ni * 16 + ln] = acc[mi][ni][r];
  }
}

// ---- Pass A2: V -> tiled/transposed/pre-swizzled Vt2 [bh][32 tiles][64 d][128 k] ----
__global__ __launch_bounds__(256) void ga_vtrans(
    const unsigned short* __restrict__ V, unsigned short* __restrict__ Vt2) {
  const int t = threadIdx.x;
  const int tile = blockIdx.x;
  const int bh = blockIdx.y;
  __shared__ unsigned short Ts[96][72];
  const unsigned short* vp = V + ((size_t)bh * S_TOK + tile * 96) * 64;
#pragma unroll
  for (int it = 0; it < 3; ++it) {
    int c = it * 256 + t;
    int s = c >> 3, d8 = c & 7;
    short8 v = *(const short8*)&vp[(size_t)s * 64 + d8 * 8];
    *(short8*)&Ts[s][d8 * 8] = v;
  }
  __syncthreads();
  unsigned short* op = Vt2 + ((size_t)bh * 32 + tile) * 8192;
#pragma unroll
  for (int it = 0; it < 4; ++it) {
    int c2 = it * 256 + t;
    int a = c2 * 8;
    int d = a >> 7;
    int kb = (a & 127) ^ ((d & 7) << 3);
    short8 o;
    if (kb < 96) {
#pragma unroll
      for (int j = 0; j < 8; ++j) o[j] = (short)Ts[kb + j][d];
    } else {
#pragma unroll
      for (int j = 0; j < 8; ++j) o[j] = 0;
    }
    *(short8*)&op[a] = o;
  }
}

// ------- Pass B: swapped-QK^T 16x16 MFMA attention, LDS-staged K/V (R6) -----
__global__ __launch_bounds__(256) void ga_attn16(
    const unsigned short* __restrict__ Q, const unsigned short* __restrict__ Kg,
    const unsigned short* __restrict__ Vt2, const float* __restrict__ rowtab,
    const float* __restrict__ coltab, float* __restrict__ Opart,
    float* __restrict__ Lpart, int tiles_per_split) {
  const int tid = threadIdx.x;
  const int w = tid >> 6;
  const int l = tid & 63;
  const int g = l >> 4;
  const int ln = l & 15;
  const int bh = blockIdx.y;
  const int sp = blockIdx.z;
  const int h = bh & 7;
  const int q0 = blockIdx.x * 128 + w * 32;

  __shared__ float rtab[127];
  __shared__ float ctab[95];
  __shared__ unsigned short Klds[6144];
  __shared__ unsigned short Vlds[8192];
  __shared__ unsigned int Pw[4][512];
  for (int i = tid; i < 127; i += 256) rtab[i] = rowtab[i * 8 + h] * 1.44269504f;
  for (int i = tid; i < 95; i += 256) ctab[i] = coltab[i * 8 + h] * 1.44269504f;
  __syncthreads();

  const unsigned short* Qp = Q + (size_t)bh * S_TOK * 64;
  const unsigned short* Kp = Kg + (size_t)bh * S_TOK * 64;
  const unsigned short* Vp = Vt2 + (size_t)bh * 32 * 8192;

  int qr[2], qc[2];
  short8 qf[2][2];
  float ctr[2][3][4];
#pragma unroll
  for (int u = 0; u < 2; ++u) {
    const int q = q0 + u * 16 + ln;
    qr[u] = q / 48;
    qc[u] = q - qr[u] * 48;
    qf[u][0] = *(const short8*)&Qp[(size_t)q * 64 + g * 8];
    qf[u][1] = *(const short8*)&Qp[(size_t)q * 64 + 32 + g * 8];
    const float* cb = &ctab[qc[u] - g * 4 + 47];
#pragma unroll
    for (int m = 0; m < 3; ++m)
#pragma unroll
      for (int r = 0; r < 4; ++r) ctr[u][m][r] = cb[-(16 * m + r)];
  }

  floatx4 o_acc[2][4];
#pragma unroll
  for (int u = 0; u < 2; ++u)
#pragma unroll
    for (int dt = 0; dt < 4; ++dt)
#pragma unroll
      for (int r = 0; r < 4; ++r) o_acc[u][dt][r] = 0.f;
  float lsum[2] = {0.f, 0.f};

  const int t0 = sp * tiles_per_split;
  for (int t = t0; t < t0 + tiles_per_split; ++t) {
    __syncthreads();
    {
      const char* kg = (const char*)(Kp + (size_t)t * 96 * 64);
      const char* vg = (const char*)(Vp + (size_t)t * 8192);
#pragma unroll
      for (int i = 0; i < 3; ++i) {
        const int off = w * 3072 + i * 1024;
        gload16(kg + off + l * 16, (char*)Klds + off);
      }
#pragma unroll
      for (int i = 0; i < 4; ++i) {
        const int off = w * 4096 + i * 1024;
        gload16(vg + off + l * 16, (char*)Vlds + off);
      }
      asm volatile("s_waitcnt vmcnt(0)" ::: "memory");
      __syncthreads();
    }
    float rt[2][2];
#pragma unroll
    for (int u = 0; u < 2; ++u) {
      rt[u][0] = rtab[qr[u] + 63 - 2 * t] - 12.0f;
      rt[u][1] = rtab[qr[u] + 62 - 2 * t] - 12.0f;
    }
    const int swz = (ln & 7) << 3;
#pragma unroll
    for (int kc32 = 0; kc32 < 3; ++kc32) {
#pragma unroll
      for (int kh = 0; kh < 2; ++kh) {
        const int kt = kc32 * 2 + kh;
        const int rb = (kt * 16 + ln) * 64;
        short8 kf0 = *(const short8*)&Klds[rb + ((g * 8) ^ swz)];
        short8 kf1 = *(const short8*)&Klds[rb + ((32 + g * 8) ^ swz)];
        const int m = kt % 3, wrap = kt / 3;
#pragma unroll
        for (int u = 0; u < 2; ++u) {
          floatx4 s = {0.f, 0.f, 0.f, 0.f};
          s = __builtin_amdgcn_mfma_f32_16x16x32_bf16(kf0, qf[u][0], s, 0, 0, 0);
          s = __builtin_amdgcn_mfma_f32_16x16x32_bf16(kf1, qf[u][1], s, 0, 0, 0);
          const float rtw = rt[u][wrap];
          float e0 = __builtin_amdgcn_exp2f(s[0] + rtw + ctr[u][m][0]);
          float e1 = __builtin_amdgcn_exp2f(s[1] + rtw + ctr[u][m][1]);
          float e2 = __builtin_amdgcn_exp2f(s[2] + rtw + ctr[u][m][2]);
          float e3 = __builtin_amdgcn_exp2f(s[3] + rtw + ctr[u][m][3]);
          lsum[u] += (e0 + e1) + (e2 + e3);
          uint2 pwd;
          pwd.x = (unsigned)f2bf(e0) | ((unsigned)f2bf(e1) << 16);
          pwd.y = (unsigned)f2bf(e2) | ((unsigned)f2bf(e3) << 16);
          *(uint2*)&Pw[w][u * 256 +
                          ((ln * 16 + kh * 8 + g * 2) ^ ((ln & 3) << 2))] = pwd;
        }
      }
      short8 pf[2];
#pragma unroll
      for (int u = 0; u < 2; ++u)
        pf[u] = *(const short8*)&Pw[w][u * 256 +
                                       ((ln * 16 + g * 4) ^ ((ln & 3) << 2))];
#pragma unroll
      for (int dt = 0; dt < 4; ++dt) {
        const int vrow = dt * 16 + ln;
        short8 vf = *(const short8*)&Vlds[vrow * 128 +
                                          ((kc32 * 32 + g * 8) ^ swz)];
        o_acc[0][dt] =
            __builtin_amdgcn_mfma_f32_16x16x32_bf16(pf[0], vf, o_acc[0][dt], 0, 0, 0);
        o_acc[1][dt] =
            __builtin_amdgcn_mfma_f32_16x16x32_bf16(pf[1], vf, o_acc[1][dt], 0, 0, 0);
      }
    }
  }
  const size_t rowbase = (size_t)(sp * 16 + bh) * S_TOK;
#pragma unroll
  for (int u = 0; u < 2; ++u) {
    float lt = lsum[u] + __shfl_xor(lsum[u], 16);
    lt += __shfl_xor(lt, 32);
    if (l < 16) Lpart[rowbase + q0 + u * 16 + ln] = lt;
#pragma unroll
    for (int dt = 0; dt < 4; ++dt)
#pragma unroll
      for (int r = 0; r < 4; ++r)
        Opart[(rowbase + q0 + u * 16 + g * 4 + r) * 64 + dt * 16 + ln] =
            o_acc[u][dt][r];
  }
}

// ---- combine split-K partials -> ctx bf16 hi/lo, swizzled (A of out-GEMM) ----
template <int NS>
__global__ __launch_bounds__(256) void ga_combine(
    const float* __restrict__ Opart, const float* __restrict__ Lpart,
    unsigned short* __restrict__ ch, unsigned short* __restrict__ cl) {
  const int c = blockIdx.x * 256 + threadIdx.x;   // 393216 chunks of 8
  const int m = c >> 6;
  const int col8 = (c & 63) << 3;
  const int b = (m >= S_TOK) ? 1 : 0;
  const int q = m - b * S_TOK;
  const int h = col8 >> 6, d0 = col8 & 63;
  const int bh = b * 8 + h;
  float v[8] = {0.f, 0.f, 0.f, 0.f, 0.f, 0.f, 0.f, 0.f};
  float ls = 0.f;
#pragma unroll
  for (int s = 0; s < NS; ++s) {
    const size_t row = (size_t)(s * 16 + bh) * S_TOK + q;
    ls += Lpart[row];
    const float4 o0 = *(const float4*)&Opart[row * 64 + d0];
    const float4 o1 = *(const float4*)&Opart[row * 64 + d0 + 4];
    v[0] += o0.x; v[1] += o0.y; v[2] += o0.z; v[3] += o0.w;
    v[4] += o1.x; v[5] += o1.y; v[6] += o1.z; v[7] += o1.w;
  }
  const float inv = 1.0f / ls;
  union { unsigned short s[8]; short8 vv; } hh, ll;
#pragma unroll
  for (int e = 0; e < 8; ++e) {
    float f = v[e] * inv;
    hh.s[e] = f2bf(f);
    ll.s[e] = f2bf(f - bf2f(hh.s[e]));
  }
  const size_t dst = (size_t)m * 512 + (col8 ^ ((m & 7) << 3));
  *(short8*)&ch[dst] = hh.vv;
  *(short8*)&cl[dst] = ll.vv;
}

extern "C" void kernel_launch(void* const* d_in, const int* in_sizes, int n_in,
                              void* d_out, int out_size, void* d_ws,
                              size_t ws_size, hipStream_t stream) {
  const float* x = (const float*)d_in[0];       // [2,64,48,512]
  const float* w_qkv = (const float*)d_in[1];   // [512,1536]
  const float* w_out = (const float*)d_in[2];   // [512,512]
  const float* rrow = (const float*)d_in[3];    // [127,8]
  const float* rcol = (const float*)d_in[4];    // [95,8]
  float* out = (float*)d_out;                   // [6144,512]

  unsigned short* ws16 = (unsigned short*)d_ws;
  unsigned short* xh = ws16;                    // 3145728 (later ctx_hi)
  unsigned short* xl = xh + 3145728;            // 3145728 (later ctx_lo)
  unsigned short* wqh = xl + 3145728;           // 786432
  unsigned short* wql = wqh + 786432;
  unsigned short* woh = wql + 786432;           // 262144
  unsigned short* wol = woh + 262144;
  unsigned short* Qb = wol + 262144;            // 3145728
  unsigned short* Kb = Qb + 3145728;
  unsigned short* Vb = Kb + 3145728;
  unsigned short* Vt2 = Vb + 3145728;           // 4194304
  float* Opart = (float*)(Vt2 + 4194304);
  const size_t base_bytes = (size_t)22020096 * 2;
  const size_t per_split = (size_t)(3145728 + 49152) * 4;
  int nsplit = (ws_size >= base_bytes + 4 * per_split) ? 4
             : (ws_size >= base_bytes + 2 * per_split) ? 2 : 1;
  float* Lpart = Opart + (size_t)nsplit * 3145728;

  ga_conv_x<<<1536, 256, 0, stream>>>(x, xh, xl);
  ga_conv_wt<<<dim3(8, 24), 256, 0, stream>>>(w_qkv, wqh, wql, 1536);
  ga_conv_wt<<<dim3(8, 8), 256, 0, stream>>>(w_out, woh, wol, 512);
  ga_mm3<128, 128, 0><<<dim3(48, 12), 256, 0, stream>>>(
      xh, xl, wqh, wql, Qb, Kb, Vb, nullptr);
  ga_vtrans<<<dim3(32, 16), 256, 0, stream>>>(Vb, Vt2);
  ga_attn16<<<dim3(24, 16, nsplit), 256, 0, stream>>>(
      Qb, Kb, Vt2, rrow, rcol, Opart, Lpart, 32 / nsplit);
  if (nsplit == 4)
    ga_combine<4><<<1536, 256, 0, stream>>>(Opart, Lpart, xh, xl);
  else if (nsplit == 2)
    ga_combine<2><<<1536, 256, 0, stream>>>(Opart, Lpart, xh, xl);
  else
    ga_combine<1><<<1536, 256, 0, stream>>>(Opart, Lpart, xh, xl);
  ga_mm3<64, 64, 1><<<dim3(96, 8), 256, 0, stream>>>(
      xh, xl, woh, wol, nullptr, nullptr, nullptr, out);
}

// Round 8
// 137.025 us; speedup vs baseline: 3.3043x; 1.1847x over previous
//
#include <hip/hip_runtime.h>
#include <hip/hip_bf16.h>

#define S_TOK 3072   // 64*48
#define NHEADS 8

typedef __attribute__((ext_vector_type(8))) short short8;
typedef __attribute__((ext_vector_type(4))) float floatx4;
typedef __attribute__((ext_vector_type(4))) unsigned short ushortx4;

__device__ __forceinline__ unsigned short f2bf(float f) {
  union { float f; unsigned u; } v; v.f = f;
  unsigned r = v.u + 0x7fffu + ((v.u >> 16) & 1u);   // RTN-even
  return (unsigned short)(r >> 16);
}
__device__ __forceinline__ float bf2f(unsigned short h) {
  union { unsigned u; float f; } v; v.u = (unsigned)h << 16;
  return v.f;
}
__device__ __forceinline__ unsigned pack2bf(float a, float b) {
  __hip_bfloat162 h = __float22bfloat162_rn(make_float2(a, b));
  union { __hip_bfloat162 h; unsigned u; } c; c.h = h;
  return c.u;
}
__device__ __forceinline__ void gload16(const void* g, void* l) {
  __builtin_amdgcn_global_load_lds(
      (const __attribute__((address_space(1))) unsigned int*)g,
      (__attribute__((address_space(3))) unsigned int*)l, 16, 0, 0);
}

// ---- hi/lo convert of X (no transpose), swizzled within 64-col blocks ----
__global__ __launch_bounds__(256) void ga_conv_x(
    const float* __restrict__ X, unsigned short* __restrict__ xh,
    unsigned short* __restrict__ xl) {
  const int c = blockIdx.x * 256 + threadIdx.x;   // 393216 chunks of 8
  const int m = c >> 6;
  const int c8 = (c & 63) << 3;
  const float* src = X + (size_t)m * 512 + c8;
  float4 v0 = *(const float4*)src, v1 = *(const float4*)(src + 4);
  float vv[8] = {v0.x, v0.y, v0.z, v0.w, v1.x, v1.y, v1.z, v1.w};
  union { unsigned short s[8]; short8 v; } hh, ll;
#pragma unroll
  for (int e = 0; e < 8; ++e) {
    hh.s[e] = f2bf(vv[e]);
    ll.s[e] = f2bf(vv[e] - bf2f(hh.s[e]));
  }
  const size_t dst = (size_t)m * 512 + (c8 ^ ((m & 7) << 3));
  *(short8*)&xh[dst] = hh.v;
  *(short8*)&xl[dst] = ll.v;
}

// ---- hi/lo convert + transpose of W [K=512][N] -> wT [N][512], swizzled ----
__global__ __launch_bounds__(256) void ga_conv_wt(
    const float* __restrict__ W, unsigned short* __restrict__ th,
    unsigned short* __restrict__ tl, int N) {
  const int k0 = blockIdx.x * 64, n0 = blockIdx.y * 64;
  const int t = threadIdx.x;
  __shared__ float Ts[64][65];
#pragma unroll
  for (int i = 0; i < 4; ++i) {
    const int r = (t >> 4) + i * 16, c4 = (t & 15) * 4;
    float4 v = *(const float4*)&W[(size_t)(k0 + r) * N + n0 + c4];
    Ts[r][c4] = v.x; Ts[r][c4 + 1] = v.y; Ts[r][c4 + 2] = v.z; Ts[r][c4 + 3] = v.w;
  }
  __syncthreads();
#pragma unroll
  for (int j = 0; j < 2; ++j) {
    const int chunk = t * 2 + j;         // 512 chunks of 8
    const int nl = chunk >> 3, m8 = chunk & 7;
    const int n = n0 + nl;
    const int ks = (m8 * 8) ^ ((n & 7) << 3);
    union { unsigned short s[8]; short8 v; } hh, ll;
#pragma unroll
    for (int e = 0; e < 8; ++e) {
      float f = Ts[ks + e][nl];
      hh.s[e] = f2bf(f);
      ll.s[e] = f2bf(f - bf2f(hh.s[e]));
    }
    const size_t dst = (size_t)n * 512 + k0 + m8 * 8;
    *(short8*)&th[dst] = hh.v;
    *(short8*)&tl[dst] = ll.v;
  }
}

// ---- bf16x3 MFMA GEMM: C[m][n] = A[m][512] * B[512][n], A/B pre-split hi/lo,
// pre-swizzled, B stored transposed [n][512]. WHICH=0: QKV epilogue; 1: f32 out.
template <int BM, int BN, int WHICH>
__global__ __launch_bounds__(256, 2) void ga_mm3(
    const unsigned short* __restrict__ Ah, const unsigned short* __restrict__ Al,
    const unsigned short* __restrict__ Bh, const unsigned short* __restrict__ Bl,
    unsigned short* __restrict__ Qd, unsigned short* __restrict__ Kd,
    unsigned short* __restrict__ Vd, float* __restrict__ Out) {
  const int tid = threadIdx.x;
  const int w = tid >> 6, l = tid & 63;
  const int g = l >> 4, ln = l & 15;
  const int wm = w >> 1, wn = w & 1;
  const int m0 = blockIdx.x * BM;
  const int n0 = blockIdx.y * BN;
  constexpr int MI = BM / 32;
  constexpr int NI = BN / 32;
  __shared__ unsigned short Alds[2][BM * 64];
  __shared__ unsigned short Blds[2][BN * 64];
  floatx4 acc[MI][NI];
#pragma unroll
  for (int mi = 0; mi < MI; ++mi)
#pragma unroll
    for (int ni = 0; ni < NI; ++ni)
#pragma unroll
      for (int r = 0; r < 4; ++r) acc[mi][ni][r] = 0.f;

  for (int k0 = 0; k0 < 512; k0 += 64) {
    __syncthreads();
    {
      constexpr int PWA = (BM * 128) / 4096;
      constexpr int PWB = (BN * 128) / 4096;
      const char* ga_h = (const char*)(Ah + (size_t)m0 * 512 + k0);
      const char* ga_l = (const char*)(Al + (size_t)m0 * 512 + k0);
      const char* gb_h = (const char*)(Bh + (size_t)n0 * 512 + k0);
      const char* gb_l = (const char*)(Bl + (size_t)n0 * 512 + k0);
#pragma unroll
      for (int i = 0; i < PWA; ++i) {
        const int off = (w * PWA + i) * 1024;
        const int gb = ((off >> 7) + (l >> 3)) * 1024 + (l & 7) * 16;
        gload16(ga_h + gb, (char*)&Alds[0][0] + off);
        gload16(ga_l + gb, (char*)&Alds[1][0] + off);
      }
#pragma unroll
      for (int i = 0; i < PWB; ++i) {
        const int off = (w * PWB + i) * 1024;
        const int gb = ((off >> 7) + (l >> 3)) * 1024 + (l & 7) * 16;
        gload16(gb_h + gb, (char*)&Blds[0][0] + off);
        gload16(gb_l + gb, (char*)&Blds[1][0] + off);
      }
    }
    asm volatile("s_waitcnt vmcnt(0)" ::: "memory");
    __syncthreads();
#pragma unroll
    for (int kk = 0; kk < 64; kk += 32) {
      const int kbase = kk + g * 8;
      short8 ah[MI], al[MI], bh[NI], bl[NI];
#pragma unroll
      for (int mi = 0; mi < MI; ++mi) {
        const int row = wm * (BM / 2) + mi * 16 + ln;
        const int a = row * 64 + (kbase ^ ((row & 7) << 3));
        ah[mi] = *(const short8*)&Alds[0][a];
        al[mi] = *(const short8*)&Alds[1][a];
      }
#pragma unroll
      for (int ni = 0; ni < NI; ++ni) {
        const int row = wn * (BN / 2) + ni * 16 + ln;
        const int a = row * 64 + (kbase ^ ((row & 7) << 3));
        bh[ni] = *(const short8*)&Blds[0][a];
        bl[ni] = *(const short8*)&Blds[1][a];
      }
#pragma unroll
      for (int mi = 0; mi < MI; ++mi)
#pragma unroll
        for (int ni = 0; ni < NI; ++ni) {
          acc[mi][ni] = __builtin_amdgcn_mfma_f32_16x16x32_bf16(
              ah[mi], bh[ni], acc[mi][ni], 0, 0, 0);
          acc[mi][ni] = __builtin_amdgcn_mfma_f32_16x16x32_bf16(
              al[mi], bh[ni], acc[mi][ni], 0, 0, 0);
          acc[mi][ni] = __builtin_amdgcn_mfma_f32_16x16x32_bf16(
              ah[mi], bl[ni], acc[mi][ni], 0, 0, 0);
        }
    }
  }
  if constexpr (WHICH == 0) {
    const int b = m0 / S_TOK;
    const int s_base = (m0 % S_TOK) + wm * (BM / 2);
#pragma unroll
    for (int ni = 0; ni < NI; ++ni) {
      const int ng = n0 + wn * (BN / 2) + ni * 16;
      const int which = ng >> 9;
      const int h = (ng >> 6) & 7;
      const int d = (ng & 63) + ln;
      unsigned short* hp = (which == 0 ? Qd : which == 1 ? Kd : Vd) +
                           (size_t)(b * 8 + h) * S_TOK * 64;
      const float qs = (which == 0) ? 0.18033688f : 1.0f;  // 1/8*log2e
#pragma unroll
      for (int mi = 0; mi < MI; ++mi)
#pragma unroll
        for (int r = 0; r < 4; ++r) {
          const int s = s_base + mi * 16 + g * 4 + r;
          const size_t idx =
              (size_t)s * 64 + ((which == 1) ? (d ^ ((s & 7) << 3)) : d);
          hp[idx] = f2bf(acc[mi][ni][r] * qs);
        }
    }
  } else {
#pragma unroll
    for (int mi = 0; mi < MI; ++mi)
#pragma unroll
      for (int ni = 0; ni < NI; ++ni)
#pragma unroll
        for (int r = 0; r < 4; ++r)
          Out[(size_t)(m0 + wm * (BM / 2) + mi * 16 + g * 4 + r) * 512 + n0 +
              wn * (BN / 2) + ni * 16 + ln] = acc[mi][ni][r];
  }
}

// ---- Pass A2: V -> tiled/transposed/pre-swizzled Vt2 [bh][32 tiles][64 d][128 k]
// Key axis PERMUTED per 32-chunk so PV A-frags are lane-local:
// storage pos g*8 + kh*4 + r  <-  actual key kh*16 + g*4 + r.
__global__ __launch_bounds__(256) void ga_vtrans(
    const unsigned short* __restrict__ V, unsigned short* __restrict__ Vt2) {
  const int t = threadIdx.x;
  const int tile = blockIdx.x;
  const int bh = blockIdx.y;
  __shared__ unsigned short Ts[96][72];
  const unsigned short* vp = V + ((size_t)bh * S_TOK + tile * 96) * 64;
#pragma unroll
  for (int it = 0; it < 3; ++it) {
    int c = it * 256 + t;
    int s = c >> 3, d8 = c & 7;
    short8 v = *(const short8*)&vp[(size_t)s * 64 + d8 * 8];
    *(short8*)&Ts[s][d8 * 8] = v;
  }
  __syncthreads();
  unsigned short* op = Vt2 + ((size_t)bh * 32 + tile) * 8192;
#pragma unroll
  for (int it = 0; it < 4; ++it) {
    int c2 = it * 256 + t;
    int a = c2 * 8;                        // output u16 addr (8-aligned)
    int d = a >> 7;
    int pos0 = (a & 127) ^ ((d & 7) << 3); // position base (mult of 8)
    short8 o;
    if (pos0 < 96) {
      const int base = (pos0 & 96) + ((pos0 >> 3) & 3) * 4;  // chunk*32 + g*4
#pragma unroll
      for (int j = 0; j < 8; ++j) {
        const int key = base + ((j >> 2) << 4) + (j & 3);
        o[j] = (short)Ts[key][d];
      }
    } else {
#pragma unroll
      for (int j = 0; j < 8; ++j) o[j] = 0;
    }
    *(short8*)&op[a] = o;
  }
}

// ------- Pass B: swapped-QK^T 16x16 MFMA attention, LDS-staged K/V ----------
// P kept fully in registers (key-permuted Vt2); l from ones-column MFMA.
__global__ __launch_bounds__(256) void ga_attn16(
    const unsigned short* __restrict__ Q, const unsigned short* __restrict__ Kg,
    const unsigned short* __restrict__ Vt2, const float* __restrict__ rowtab,
    const float* __restrict__ coltab, float* __restrict__ Opart,
    float* __restrict__ Lpart, int tiles_per_split) {
  const int tid = threadIdx.x;
  const int w = tid >> 6;
  const int l = tid & 63;
  const int g = l >> 4;
  const int ln = l & 15;
  const int bh = blockIdx.y;
  const int sp = blockIdx.z;
  const int h = bh & 7;
  const int q0 = blockIdx.x * 128 + w * 32;

  __shared__ float rtab[127];
  __shared__ float ctab[95];
  __shared__ unsigned short Klds[6144];
  __shared__ unsigned short Vlds[8192];
  for (int i = tid; i < 127; i += 256) rtab[i] = rowtab[i * 8 + h] * 1.44269504f;
  for (int i = tid; i < 95; i += 256) ctab[i] = coltab[i * 8 + h] * 1.44269504f;
  __syncthreads();

  const unsigned short* Qp = Q + (size_t)bh * S_TOK * 64;
  const unsigned short* Kp = Kg + (size_t)bh * S_TOK * 64;
  const unsigned short* Vp = Vt2 + (size_t)bh * 32 * 8192;

  int qr[2], qc[2];
  short8 qf[2][2];
  float ctr[2][3][4];
#pragma unroll
  for (int u = 0; u < 2; ++u) {
    const int q = q0 + u * 16 + ln;
    qr[u] = q / 48;
    qc[u] = q - qr[u] * 48;
    qf[u][0] = *(const short8*)&Qp[(size_t)q * 64 + g * 8];
    qf[u][1] = *(const short8*)&Qp[(size_t)q * 64 + 32 + g * 8];
    const float* cb = &ctab[qc[u] - g * 4 + 47];
#pragma unroll
    for (int m = 0; m < 3; ++m)
#pragma unroll
      for (int r = 0; r < 4; ++r) ctr[u][m][r] = cb[-(16 * m + r)];
  }

  short8 ones;
  {
    union { unsigned short s[8]; short8 v; } on;
#pragma unroll
    for (int j = 0; j < 8; ++j) on.s[j] = 0x3F80;  // bf16 1.0
    ones = on.v;
  }

  floatx4 o_acc[2][4];
  floatx4 o5[2];
#pragma unroll
  for (int u = 0; u < 2; ++u) {
#pragma unroll
    for (int r = 0; r < 4; ++r) o5[u][r] = 0.f;
#pragma unroll
    for (int dt = 0; dt < 4; ++dt)
#pragma unroll
      for (int r = 0; r < 4; ++r) o_acc[u][dt][r] = 0.f;
  }

  const int t0 = sp * tiles_per_split;
  for (int t = t0; t < t0 + tiles_per_split; ++t) {
    __syncthreads();
    {
      const char* kg = (const char*)(Kp + (size_t)t * 96 * 64);
      const char* vg = (const char*)(Vp + (size_t)t * 8192);
#pragma unroll
      for (int i = 0; i < 3; ++i) {
        const int off = w * 3072 + i * 1024;
        gload16(kg + off + l * 16, (char*)Klds + off);
      }
#pragma unroll
      for (int i = 0; i < 4; ++i) {
        const int off = w * 4096 + i * 1024;
        gload16(vg + off + l * 16, (char*)Vlds + off);
      }
      asm volatile("s_waitcnt vmcnt(0)" ::: "memory");
      __syncthreads();
    }
    float rt[2][2];
#pragma unroll
    for (int u = 0; u < 2; ++u) {
      rt[u][0] = rtab[qr[u] + 63 - 2 * t] - 12.0f;
      rt[u][1] = rtab[qr[u] + 62 - 2 * t] - 12.0f;
    }
    const int swz = (ln & 7) << 3;
#pragma unroll
    for (int kc32 = 0; kc32 < 3; ++kc32) {
      float e[2][2][4];
#pragma unroll
      for (int kh = 0; kh < 2; ++kh) {
        const int kt = kc32 * 2 + kh;
        const int rb = (kt * 16 + ln) * 64;
        short8 kf0 = *(const short8*)&Klds[rb + ((g * 8) ^ swz)];
        short8 kf1 = *(const short8*)&Klds[rb + ((32 + g * 8) ^ swz)];
        const int m = kt % 3, wrap = kt / 3;
#pragma unroll
        for (int u = 0; u < 2; ++u) {
          floatx4 s = {0.f, 0.f, 0.f, 0.f};
          s = __builtin_amdgcn_mfma_f32_16x16x32_bf16(kf0, qf[u][0], s, 0, 0, 0);
          s = __builtin_amdgcn_mfma_f32_16x16x32_bf16(kf1, qf[u][1], s, 0, 0, 0);
          const float rtw = rt[u][wrap];
#pragma unroll
          for (int r = 0; r < 4; ++r)
            e[u][kh][r] = __builtin_amdgcn_exp2f(s[r] + rtw + ctr[u][m][r]);
        }
      }
      short8 pf[2];
#pragma unroll
      for (int u = 0; u < 2; ++u) {
        union { unsigned uu[4]; short8 v; } pk;
        pk.uu[0] = pack2bf(e[u][0][0], e[u][0][1]);
        pk.uu[1] = pack2bf(e[u][0][2], e[u][0][3]);
        pk.uu[2] = pack2bf(e[u][1][0], e[u][1][1]);
        pk.uu[3] = pack2bf(e[u][1][2], e[u][1][3]);
        pf[u] = pk.v;
      }
#pragma unroll
      for (int dt = 0; dt < 4; ++dt) {
        const int vrow = dt * 16 + ln;
        short8 vf = *(const short8*)&Vlds[vrow * 128 +
                                          ((kc32 * 32 + g * 8) ^ swz)];
        o_acc[0][dt] =
            __builtin_amdgcn_mfma_f32_16x16x32_bf16(pf[0], vf, o_acc[0][dt], 0, 0, 0);
        o_acc[1][dt] =
            __builtin_amdgcn_mfma_f32_16x16x32_bf16(pf[1], vf, o_acc[1][dt], 0, 0, 0);
      }
      o5[0] = __builtin_amdgcn_mfma_f32_16x16x32_bf16(pf[0], ones, o5[0], 0, 0, 0);
      o5[1] = __builtin_amdgcn_mfma_f32_16x16x32_bf16(pf[1], ones, o5[1], 0, 0, 0);
    }
  }
  const size_t rowbase = (size_t)(sp * 16 + bh) * S_TOK;
#pragma unroll
  for (int u = 0; u < 2; ++u) {
    if (ln == 0) {
#pragma unroll
      for (int r = 0; r < 4; ++r)
        Lpart[rowbase + q0 + u * 16 + g * 4 + r] = o5[u][r];
    }
#pragma unroll
    for (int dt = 0; dt < 4; ++dt)
#pragma unroll
      for (int r = 0; r < 4; ++r)
        Opart[(rowbase + q0 + u * 16 + g * 4 + r) * 64 + dt * 16 + ln] =
            o_acc[u][dt][r];
  }
}

// ---- combine split-K partials -> ctx bf16 hi/lo, swizzled (A of out-GEMM) ----
template <int NS>
__global__ __launch_bounds__(256) void ga_combine(
    const float* __restrict__ Opart, const float* __restrict__ Lpart,
    unsigned short* __restrict__ ch, unsigned short* __restrict__ cl) {
  const int c = blockIdx.x * 256 + threadIdx.x;   // 393216 chunks of 8
  const int m = c >> 6;
  const int col8 = (c & 63) << 3;
  const int b = (m >= S_TOK) ? 1 : 0;
  const int q = m - b * S_TOK;
  const int h = col8 >> 6, d0 = col8 & 63;
  const int bh = b * 8 + h;
  float v[8] = {0.f, 0.f, 0.f, 0.f, 0.f, 0.f, 0.f, 0.f};
  float ls = 0.f;
#pragma unroll
  for (int s = 0; s < NS; ++s) {
    const size_t row = (size_t)(s * 16 + bh) * S_TOK + q;
    ls += Lpart[row];
    const float4 o0 = *(const float4*)&Opart[row * 64 + d0];
    const float4 o1 = *(const float4*)&Opart[row * 64 + d0 + 4];
    v[0] += o0.x; v[1] += o0.y; v[2] += o0.z; v[3] += o0.w;
    v[4] += o1.x; v[5] += o1.y; v[6] += o1.z; v[7] += o1.w;
  }
  const float inv = 1.0f / ls;
  union { unsigned short s[8]; short8 vv; } hh, ll;
#pragma unroll
  for (int e = 0; e < 8; ++e) {
    float f = v[e] * inv;
    hh.s[e] = f2bf(f);
    ll.s[e] = f2bf(f - bf2f(hh.s[e]));
  }
  const size_t dst = (size_t)m * 512 + (col8 ^ ((m & 7) << 3));
  *(short8*)&ch[dst] = hh.vv;
  *(short8*)&cl[dst] = ll.vv;
}

extern "C" void kernel_launch(void* const* d_in, const int* in_sizes, int n_in,
                              void* d_out, int out_size, void* d_ws,
                              size_t ws_size, hipStream_t stream) {
  const float* x = (const float*)d_in[0];       // [2,64,48,512]
  const float* w_qkv = (const float*)d_in[1];   // [512,1536]
  const float* w_out = (const float*)d_in[2];   // [512,512]
  const float* rrow = (const float*)d_in[3];    // [127,8]
  const float* rcol = (const float*)d_in[4];    // [95,8]
  float* out = (float*)d_out;                   // [6144,512]

  unsigned short* ws16 = (unsigned short*)d_ws;
  unsigned short* xh = ws16;                    // 3145728 (later ctx_hi)
  unsigned short* xl = xh + 3145728;            // 3145728 (later ctx_lo)
  unsigned short* wqh = xl + 3145728;           // 786432
  unsigned short* wql = wqh + 786432;
  unsigned short* woh = wql + 786432;           // 262144
  unsigned short* wol = woh + 262144;
  unsigned short* Qb = wol + 262144;            // 3145728
  unsigned short* Kb = Qb + 3145728;
  unsigned short* Vb = Kb + 3145728;
  unsigned short* Vt2 = Vb + 3145728;           // 4194304
  float* Opart = (float*)(Vt2 + 4194304);
  const size_t base_bytes = (size_t)22020096 * 2;
  const size_t per_split = (size_t)(3145728 + 49152) * 4;
  int nsplit = (ws_size >= base_bytes + 2 * per_split) ? 2 : 1;
  float* Lpart = Opart + (size_t)nsplit * 3145728;

  ga_conv_x<<<1536, 256, 0, stream>>>(x, xh, xl);
  ga_conv_wt<<<dim3(8, 24), 256, 0, stream>>>(w_qkv, wqh, wql, 1536);
  ga_conv_wt<<<dim3(8, 8), 256, 0, stream>>>(w_out, woh, wol, 512);
  ga_mm3<128, 128, 0><<<dim3(48, 12), 256, 0, stream>>>(
      xh, xl, wqh, wql, Qb, Kb, Vb, nullptr);
  ga_vtrans<<<dim3(32, 16), 256, 0, stream>>>(Vb, Vt2);
  ga_attn16<<<dim3(24, 16, nsplit), 256, 0, stream>>>(
      Qb, Kb, Vt2, rrow, rcol, Opart, Lpart, 32 / nsplit);
  if (nsplit == 2)
    ga_combine<2><<<1536, 256, 0, stream>>>(Opart, Lpart, xh, xl);
  else
    ga_combine<1><<<1536, 256, 0, stream>>>(Opart, Lpart, xh, xl);
  ga_mm3<64, 64, 1><<<dim3(96, 8), 256, 0, stream>>>(
      xh, xl, woh, wol, nullptr, nullptr, nullptr, out);
}